// Round 10
// baseline (2298.198 us; speedup 1.0000x reference)
//
#include <hip/hip_runtime.h>
#include <math.h>

#define B 4
#define N 32768
#define D 131
#define S 1024
#define RAD2 0.1f      // reference compares d2 <= RADIUS (=0.1) on SQUARED distance
#define G 8            // FPS blocks per batch (sync participants)
#define TPB 512        // threads per fps/copy block
#define PPT 8          // points per thread
#define NFPS (B * G)   // 32 fps blocks
#define COPY_BLOCKS 192
#define SLOT_STRIDE 8  // u64s per slot (64B padding: no false sharing)

// ---------------------------------------------------------------------------
// Pack pts = x[:,:,:3] into SoA (px|py|pz) AND packed float4 {x,y,z,0}.
// ---------------------------------------------------------------------------
__global__ void pack_kernel(const float* __restrict__ x, float* __restrict__ ws) {
    int i = blockIdx.x * blockDim.x + threadIdx.x;
    if (i < B * N) {
        const float* __restrict__ s = x + (size_t)i * D;
        float a = s[0], bb = s[1], c = s[2];
        ws[i]             = a;
        ws[B * N + i]     = bb;
        ws[2 * B * N + i] = c;
        float4* w4 = (float4*)(ws + (size_t)3 * B * N);
        w4[i] = make_float4(a, bb, c, 0.0f);
    }
}

// ---------------------------------------------------------------------------
// Fused FPS + copy. 224 blocks x 512 thr.
// FPS blocks [0,32): 8 blocks/batch, 8 pts/thread, coords staged in LDS
// (24KB: immune to the atomic-alias reload paranoia that kept evicting the
// register copies in R5-R9), lcl[8] in VGPRs.
// Per step: LDS coord reads -> d2/min update -> wave butterfly -> LDS wave
// keys -> barrier -> wave0: block key -> 64B-padded slot store (agent,
// relaxed, self-tagged) -> STAGGERED 4-DEEP PIPELINED POLL of the 8 slots
// (4 loads in flight, issued ~130cyc apart via s_sleep -> detect quantum
// ~RT/4 instead of RT) -> per-lane candidate coord prefetch overlapped with
// 3-stage key reduce -> ballot/shfl winner coords -> LDS bcast {coords,tag};
// other waves spin on the LDS tag only (no global traffic).
// Copy blocks [32,224): grid-stride float4 copy of x (fps uses ~0 HBM BW).
// Key: [f32 val:32][32767-idx:15][0:6][tag=s+1:11]; equal tags => u64 max =
// (max val, then min idx) = exact reference tie-break.
// Slot double-buffer safety: buf overwritten at s+2 only after the writer's
// s+1 poll succeeded => every consumer finished reading step s.
// LDS tag safety: tag s+1 published only after barrier(s), which all waves
// reach only after consuming bcast(s-1); coords fenced before tag.
// ---------------------------------------------------------------------------
__launch_bounds__(TPB)
__global__ void fps_copy_kernel(const float* __restrict__ x,
                                const float* __restrict__ ws,
                                unsigned long long* __restrict__ gslot, // [B][2][G] 64B-strided
                                float* __restrict__ out_idx,
                                int* __restrict__ idx_int,
                                float* __restrict__ out_x) {
    if (blockIdx.x >= NFPS) {
        const size_t total4 = (size_t)B * N * D / 4;
        const float4* __restrict__ src = (const float4*)x;
        float4* __restrict__ dst = (float4*)out_x;
        for (size_t i = (size_t)(blockIdx.x - NFPS) * TPB + threadIdx.x; i < total4;
             i += (size_t)COPY_BLOCKS * TPB)
            dst[i] = src[i];
        return;
    }

    const int b = blockIdx.x >> 3;          // batch
    const int g = blockIdx.x & 7;           // participant id within batch
    const int t = threadIdx.x;
    const int lane = t & 63;
    const int w = t >> 6;                   // wave 0..7

    __shared__ float s_x[N / G], s_y[N / G], s_z[N / G];   // 24 KB coords
    __shared__ unsigned long long s_wk[2][8];              // wave keys (dbuf)
    __shared__ float s_bc[3];                              // bcast centroid
    __shared__ unsigned s_tag;                             // monotone step tag

    const float* __restrict__ px = ws + (size_t)b * N;
    const float* __restrict__ py = ws + (size_t)(B + b) * N;
    const float* __restrict__ pz = ws + (size_t)(2 * B + b) * N;
    const float4* __restrict__ p4 = (const float4*)(ws + (size_t)3 * B * N) + (size_t)b * N;
    unsigned long long* __restrict__ slots = gslot + (size_t)b * 2 * G * SLOT_STRIDE;

    const int base = g * (N / G);
    float lcl[PPT];
    #pragma unroll
    for (int i = 0; i < PPT / 2; ++i) {
        const int l = 2 * t + 2 * TPB * i;          // local index in [0, 2048)
        *(float2*)&s_x[l] = *(const float2*)&px[base + l];
        *(float2*)&s_y[l] = *(const float2*)&py[base + l];
        *(float2*)&s_z[l] = *(const float2*)&pz[base + l];
        lcl[2*i] = INFINITY; lcl[2*i+1] = INFINITY;
    }
    if (t == 0) s_tag = 0;
    __syncthreads();

    float4 cq = p4[0];
    float cx = cq.x, cy = cq.y, cz = cq.z;   // centroid 0 (ref starts at sel=0)

    for (int s = 0; s < S; ++s) {
        float best = -INFINITY;
        int   bidx = 0;
        #pragma unroll
        for (int i = 0; i < PPT / 2; ++i) {
            const int l = 2 * t + 2 * TPB * i;
            float2 vx = *(const float2*)&s_x[l];
            float2 vy = *(const float2*)&s_y[l];
            float2 vz = *(const float2*)&s_z[l];
            {
                float dx = __fsub_rn(cx, vx.x);
                float dy = __fsub_rn(cy, vy.x);
                float dz = __fsub_rn(cz, vz.x);
                float d2 = __fadd_rn(__fadd_rn(__fmul_rn(dx, dx), __fmul_rn(dy, dy)),
                                     __fmul_rn(dz, dz));
                float c = fminf(lcl[2*i], d2);
                lcl[2*i] = c;
                if (c > best) { best = c; bidx = base + l; }   // strict >: smallest p
            }
            {
                float dx = __fsub_rn(cx, vx.y);
                float dy = __fsub_rn(cy, vy.y);
                float dz = __fsub_rn(cz, vz.y);
                float d2 = __fadd_rn(__fadd_rn(__fmul_rn(dx, dx), __fmul_rn(dy, dy)),
                                     __fmul_rn(dz, dz));
                float c = fminf(lcl[2*i+1], d2);
                lcl[2*i+1] = c;
                if (c > best) { best = c; bidx = base + l + 1; }
            }
        }

        // intra-wave butterfly argmax on (value, smallest idx)
        unsigned hi  = __float_as_uint(best);
        unsigned lo2 = (unsigned)(32767 - bidx);
        #define FPS_COMBINE(OHI, OLO) \
            { unsigned _oh = (OHI), _ol = (OLO); \
              if (_oh > hi || (_oh == hi && _ol > lo2)) { hi = _oh; lo2 = _ol; } }
        { unsigned a = (unsigned)__builtin_amdgcn_update_dpp(0, (int)hi, 0xB1, 0xf, 0xf, true);
          unsigned c2 = (unsigned)__builtin_amdgcn_update_dpp(0, (int)lo2, 0xB1, 0xf, 0xf, true);
          FPS_COMBINE(a, c2); }
        { unsigned a = (unsigned)__builtin_amdgcn_update_dpp(0, (int)hi, 0x4E, 0xf, 0xf, true);
          unsigned c2 = (unsigned)__builtin_amdgcn_update_dpp(0, (int)lo2, 0x4E, 0xf, 0xf, true);
          FPS_COMBINE(a, c2); }
        { unsigned a = (unsigned)__builtin_amdgcn_update_dpp(0, (int)hi, 0x141, 0xf, 0xf, true);
          unsigned c2 = (unsigned)__builtin_amdgcn_update_dpp(0, (int)lo2, 0x141, 0xf, 0xf, true);
          FPS_COMBINE(a, c2); }
        { unsigned a = (unsigned)__builtin_amdgcn_update_dpp(0, (int)hi, 0x140, 0xf, 0xf, true);
          unsigned c2 = (unsigned)__builtin_amdgcn_update_dpp(0, (int)lo2, 0x140, 0xf, 0xf, true);
          FPS_COMBINE(a, c2); }
        { unsigned a = (unsigned)__builtin_amdgcn_ds_swizzle((int)hi, 0x401F);
          unsigned c2 = (unsigned)__builtin_amdgcn_ds_swizzle((int)lo2, 0x401F);
          FPS_COMBINE(a, c2); }
        { unsigned a = (unsigned)__shfl_xor((int)hi, 32, 64);
          unsigned c2 = (unsigned)__shfl_xor((int)lo2, 32, 64);
          FPS_COMBINE(a, c2); }
        #undef FPS_COMBINE

        const int buf = s & 1;
        const unsigned tag = (unsigned)(s + 1);
        const unsigned long long mykey = ((unsigned long long)hi << 32) |
                                         ((unsigned long long)lo2 << 17) | tag;
        if (lane == 0) s_wk[buf][w] = mykey;
        __syncthreads();                             // the ONLY barrier per step

        if (w == 0) {
            // block key = max of 8 wave keys
            unsigned long long bk = s_wk[buf][0];
            #pragma unroll
            for (int j = 1; j < 8; ++j) { unsigned long long v = s_wk[buf][j]; if (v > bk) bk = v; }
            if (lane == 0)
                __hip_atomic_store(&slots[((size_t)buf * G + g) * SLOT_STRIDE], bk,
                                   __ATOMIC_RELAXED, __HIP_MEMORY_SCOPE_AGENT);

            // staggered 4-deep pipelined poll: lane i watches slot i&7
            unsigned long long* myslot =
                &slots[((size_t)buf * G + (lane & 7)) * SLOT_STRIDE];
            #define POLL() __hip_atomic_load(myslot, __ATOMIC_RELAXED, __HIP_MEMORY_SCOPE_AGENT)
            unsigned long long q0, q1, q2, q3, kko;
            q0 = POLL(); __builtin_amdgcn_s_sleep(2);
            q1 = POLL(); __builtin_amdgcn_s_sleep(2);
            q2 = POLL(); __builtin_amdgcn_s_sleep(2);
            q3 = POLL();
            for (;;) {
                if (!__any((unsigned)(q0 & 0x7FFull) != tag)) { kko = q0; break; }
                q0 = POLL();
                if (!__any((unsigned)(q1 & 0x7FFull) != tag)) { kko = q1; break; }
                q1 = POLL();
                if (!__any((unsigned)(q2 & 0x7FFull) != tag)) { kko = q2; break; }
                q2 = POLL();
                if (!__any((unsigned)(q3 & 0x7FFull) != tag)) { kko = q3; break; }
                q3 = POLL();
            }
            #undef POLL

            // prefetch per-lane candidate coords, OVERLAPPED with key reduce
            const int idxc = 32767 - (int)((kko >> 17) & 0x7FFF);
            const float4 cand = p4[idxc];

            unsigned long long kk = kko;
            #pragma unroll
            for (int off = 1; off < 8; off <<= 1) {
                unsigned long long o = (unsigned long long)__shfl_xor((long long)kk, off, 64);
                if (o > kk) kk = o;
            }
            unsigned long long mask = __ballot(kko == kk);
            int src = (int)(__ffsll((unsigned long long)mask) - 1);
            cx = __shfl(cand.x, src, 64);
            cy = __shfl(cand.y, src, 64);
            cz = __shfl(cand.z, src, 64);

            if (lane == 0) {
                s_bc[0] = cx; s_bc[1] = cy; s_bc[2] = cz;
                __threadfence_block();               // coords visible before tag
                __hip_atomic_store(&s_tag, tag, __ATOMIC_RELAXED,
                                   __HIP_MEMORY_SCOPE_WORKGROUP);
                if (g == 0) {
                    int sel = 32767 - (int)((kk >> 17) & 0x7FFF);
                    out_idx[(size_t)b * S + s] = (float)sel;
                    idx_int[b * S + s] = sel;
                }
            }
        } else {
            // spin on the local LDS tag (no global traffic), then read coords
            while (__hip_atomic_load(&s_tag, __ATOMIC_RELAXED,
                                     __HIP_MEMORY_SCOPE_WORKGROUP) != tag) {}
            __threadfence_block();
            cx = s_bc[0]; cy = s_bc[1]; cz = s_bc[2];
        }
    }
}

// ---------------------------------------------------------------------------
// Ball query counts: one block (256 thr) per (batch, centroid).
// ---------------------------------------------------------------------------
__launch_bounds__(256)
__global__ void ballq_kernel(const float* __restrict__ ws,
                             const int* __restrict__ idx_int,
                             float* __restrict__ out_counts) {
    __shared__ int s_part[4];
    const int b = blockIdx.x >> 10;
    const int j = blockIdx.x & 1023;
    const int t = threadIdx.x;
    const float* __restrict__ px = ws + (size_t)b * N;
    const float* __restrict__ py = ws + (size_t)(B + b) * N;
    const float* __restrict__ pz = ws + (size_t)(2 * B + b) * N;

    const int ci = idx_int[b * S + j];
    const float cx = px[ci], cy = py[ci], cz = pz[ci];

    int cnt = 0;
    #pragma unroll 4
    for (int p = t; p < N; p += 256) {
        float dx = __fsub_rn(cx, px[p]);
        float dy = __fsub_rn(cy, py[p]);
        float dz = __fsub_rn(cz, pz[p]);
        float d2 = __fadd_rn(__fadd_rn(__fmul_rn(dx, dx), __fmul_rn(dy, dy)),
                             __fmul_rn(dz, dz));
        cnt += (d2 <= RAD2) ? 1 : 0;
    }
    #pragma unroll
    for (int off = 1; off < 64; off <<= 1)
        cnt += __shfl_xor(cnt, off, 64);
    if ((t & 63) == 0) s_part[t >> 6] = cnt;
    __syncthreads();
    if (t == 0)
        out_counts[b * S + j] = (float)(s_part[0] + s_part[1] + s_part[2] + s_part[3]);
}

// ---------------------------------------------------------------------------
extern "C" void kernel_launch(void* const* d_in, const int* in_sizes, int n_in,
                              void* d_out, int out_size, void* d_ws, size_t ws_size,
                              hipStream_t stream) {
    const float* x = (const float*)d_in[0];
    float* out = (float*)d_out;
    float* ws = (float*)d_ws;   // px|py|pz (3BN) | float4 pack (4BN) | idx ints | slots
    int* idx_int = (int*)(ws + (size_t)7 * B * N);
    unsigned long long* gslot = (unsigned long long*)(idx_int + B * S);

    float* out_x      = out;                         // B*N*D floats
    float* out_idx    = out + (size_t)B * N * D;     // B*S floats (idx as f32)
    float* out_counts = out_idx + (size_t)B * S;     // B*S floats (counts as f32)

    // zero the padded slot array: B*2*G slots * 64B = 4 KB
    hipMemsetAsync(gslot, 0,
                   (size_t)B * 2 * G * SLOT_STRIDE * sizeof(unsigned long long), stream);

    hipLaunchKernelGGL(pack_kernel, dim3((B * N + 255) / 256), dim3(256), 0, stream, x, ws);
    hipLaunchKernelGGL(fps_copy_kernel, dim3(NFPS + COPY_BLOCKS), dim3(TPB), 0, stream,
                       x, ws, gslot, out_idx, idx_int, out_x);
    hipLaunchKernelGGL(ballq_kernel, dim3(B * S), dim3(256), 0, stream, ws, idx_int, out_counts);
}